// Round 1
// baseline (276.189 us; speedup 1.0000x reference)
//
#include <hip/hip_runtime.h>
#include <hip/hip_bf16.h>
#include <cmath>

typedef float f32x4 __attribute__((ext_vector_type(4)));
typedef __bf16 bf16x8 __attribute__((ext_vector_type(8)));
typedef __bf16 bf16x4 __attribute__((ext_vector_type(4)));

#define C_IN 384
#define C_OUT 384
#define SPB 4096      // spatial per batch image (64*64)
#define NPIX 131072   // 32 * 4096 total pixels

// ---------------------------------------------------------------------------
// Kernel 1: per-pixel LayerNorm stats (mean, rstd) over the channel dim.
// x is [B][C][S]; consecutive threads -> consecutive s (coalesced float2).
// ---------------------------------------------------------------------------
__global__ __launch_bounds__(256) void ppl_stats_kernel(const float* __restrict__ x,
                                                        float* __restrict__ mu,
                                                        float* __restrict__ rs) {
  const int idx = blockIdx.x * 256 + threadIdx.x;  // 0..65535, 2 pixels each
  const int p0 = idx * 2;
  const int b = p0 >> 12;
  const int s = p0 & 4095;
  const float* xb = x + (size_t)b * (C_IN * SPB) + s;
  float s0 = 0.f, s1 = 0.f, q0 = 0.f, q1 = 0.f;
#pragma unroll 4
  for (int c = 0; c < C_IN; ++c) {
    float2 v = *reinterpret_cast<const float2*>(xb + (size_t)c * SPB);
    s0 += v.x; s1 += v.y;
    q0 += v.x * v.x; q1 += v.y * v.y;
  }
  const float inv = 1.0f / (float)C_IN;
  const float m0 = s0 * inv, m1 = s1 * inv;
  const float v0 = q0 * inv - m0 * m0;
  const float v1 = q1 * inv - m1 * m1;
  mu[p0] = m0; mu[p0 + 1] = m1;
  rs[p0] = rsqrtf(v0 + 1e-5f);
  rs[p0 + 1] = rsqrtf(v1 + 1e-5f);
}

// ---------------------------------------------------------------------------
// Kernel 2: fold LN affine into the weights.
//   Wp[o][c] = bf16(W[o][c] * gamma[c])
//   t1[o]    = sum_c float(Wp[o][c])            (rounded, for consistency)
//   t2[o]    = sum_c beta[c] * W[o][c] + b[o]
// ---------------------------------------------------------------------------
__global__ __launch_bounds__(128) void ppl_prep_kernel(const float* __restrict__ W,
                                                       const float* __restrict__ gamma,
                                                       const float* __restrict__ beta,
                                                       const float* __restrict__ bias,
                                                       __bf16* __restrict__ Wp,
                                                       float* __restrict__ t1,
                                                       float* __restrict__ t2) {
  const int o = blockIdx.x;
  const int t = threadIdx.x;
  const float* row = W + o * C_IN;
  float s1 = 0.f, s2 = 0.f;
  for (int c = t; c < C_IN; c += 128) {
    const float w = row[c];
    const __bf16 wq = (__bf16)(w * gamma[c]);
    Wp[o * C_IN + c] = wq;
    s1 += (float)wq;
    s2 += beta[c] * w;
  }
  // reduce across the 2 waves
#pragma unroll
  for (int off = 32; off > 0; off >>= 1) {
    s1 += __shfl_down(s1, off);
    s2 += __shfl_down(s2, off);
  }
  __shared__ float red[2][2];
  if ((t & 63) == 0) { red[t >> 6][0] = s1; red[t >> 6][1] = s2; }
  __syncthreads();
  if (t == 0) {
    t1[o] = red[0][0] + red[1][0];
    t2[o] = red[0][1] + red[1][1] + bias[o];
  }
}

// ---------------------------------------------------------------------------
// Kernel 3: GEMM + epilogue.
//   D[o][p] = sum_c Wp[o][c] * bf16(x[p][c])   (MFMA 16x16x32 bf16, fp32 acc)
//   y = rs*D - rs*mu*t1[o] + t2[o];  out = gelu_exact(y)  -> NCHW fp32
// Tiles: BO=64 out-channels (MFMA M), BP=128 pixels (MFMA N), BK=32.
// LDS rows padded to 40 bf16 (80 B) so fragment ds_read_b128 is 16B-aligned
// and staging writes spread banks (non-pow2 stride).
// ---------------------------------------------------------------------------
#define BO 64
#define BP 128
#define BK 32
#define LDK 40

__global__ __launch_bounds__(256) void ppl_gemm_kernel(const float* __restrict__ x,
                                                       const __bf16* __restrict__ Wp,
                                                       const float* __restrict__ mug,
                                                       const float* __restrict__ rsg,
                                                       const float* __restrict__ t1g,
                                                       const float* __restrict__ t2g,
                                                       float* __restrict__ out) {
  __shared__ __bf16 Xs[BP][LDK];  // pixel-major, K-contiguous (B operand)
  __shared__ __bf16 Wl[BO][LDK];  // o-major,    K-contiguous (A operand)

  const int tid = threadIdx.x;
  const int bid = blockIdx.x;
  const int tile_o = bid % (C_OUT / BO);  // fastest-varying: 6 o-tiles share an x-slab
  const int tile_p = bid / (C_OUT / BO);
  const int p0 = tile_p * BP;   // global pixel base (128-aligned -> single batch)
  const int b = p0 >> 12;
  const int s0 = p0 & 4095;
  const int o0 = tile_o * BO;

  const float* xbase = x + (size_t)b * (C_IN * SPB) + s0;

  const int lane = tid & 63;
  const int wid = tid >> 6;
  const int wm = wid >> 1;  // o-dim wave (2 x 32)
  const int wn = wid & 1;   // p-dim wave (2 x 64)

  // staging maps
  const int sp = tid & 127;   // pixel within tile (Xs row)
  const int scg = tid >> 7;   // channel interleave group
  const int wrow = tid >> 2;  // Wl row
  const int wc0 = (tid & 3) * 8;

  f32x4 acc[2][4];
#pragma unroll
  for (int m = 0; m < 2; ++m)
#pragma unroll
    for (int n = 0; n < 4; ++n) acc[m][n] = (f32x4){0.f, 0.f, 0.f, 0.f};

  const int kgrp = (lane >> 4) * 8;
  const int fr = lane & 15;

  for (int k0 = 0; k0 < C_IN; k0 += BK) {
    // ---- stage X tile: gather 4 channels per pixel -> one b64 LDS write ----
#pragma unroll
    for (int g = 0; g < 4; ++g) {
      const int c = scg * 4 + g * 8;  // {0,8,16,24} or {4,12,20,28}
      const float* src = xbase + (size_t)(k0 + c) * SPB + sp;
      bf16x4 v;
      v[0] = (__bf16)src[0];
      v[1] = (__bf16)src[SPB];
      v[2] = (__bf16)src[2 * SPB];
      v[3] = (__bf16)src[3 * SPB];
      *reinterpret_cast<bf16x4*>(&Xs[sp][c]) = v;
    }
    // ---- stage W tile: one 16B load + 16B LDS write ----
    {
      const bf16x8 wv = *reinterpret_cast<const bf16x8*>(Wp + (size_t)(o0 + wrow) * C_IN + k0 + wc0);
      *reinterpret_cast<bf16x8*>(&Wl[wrow][wc0]) = wv;
    }
    __syncthreads();

    // ---- fragments + MFMA ----
    bf16x8 afrag[2], bfrag[4];
#pragma unroll
    for (int m = 0; m < 2; ++m)
      afrag[m] = *reinterpret_cast<const bf16x8*>(&Wl[wm * 32 + m * 16 + fr][kgrp]);
#pragma unroll
    for (int n = 0; n < 4; ++n)
      bfrag[n] = *reinterpret_cast<const bf16x8*>(&Xs[wn * 64 + n * 16 + fr][kgrp]);
#pragma unroll
    for (int m = 0; m < 2; ++m)
#pragma unroll
      for (int n = 0; n < 4; ++n)
        acc[m][n] = __builtin_amdgcn_mfma_f32_16x16x32_bf16(afrag[m], bfrag[n], acc[m][n], 0, 0, 0);

    __syncthreads();
  }

  // ---- epilogue: LN correction + bias + exact GELU, store NCHW ----
  const int rowg = lane >> 4;
  float t1v[2][4], t2v[2][4];
#pragma unroll
  for (int m = 0; m < 2; ++m)
#pragma unroll
    for (int r = 0; r < 4; ++r) {
      const int o = o0 + wm * 32 + m * 16 + rowg * 4 + r;
      t1v[m][r] = t1g[o];
      t2v[m][r] = t2g[o];
    }
#pragma unroll
  for (int n = 0; n < 4; ++n) {
    const int pl = wn * 64 + n * 16 + fr;  // pixel within tile
    const float muv = mug[p0 + pl];
    const float rsv = rsg[p0 + pl];
    const int s = s0 + pl;
#pragma unroll
    for (int m = 0; m < 2; ++m) {
#pragma unroll
      for (int r = 0; r < 4; ++r) {
        const int o = o0 + wm * 32 + m * 16 + rowg * 4 + r;
        const float y = rsv * acc[m][n][r] - rsv * muv * t1v[m][r] + t2v[m][r];
        const float ge = 0.5f * y * (1.0f + erff(y * 0.7071067811865475f));
        out[((size_t)(b * C_OUT + o) << 12) + s] = ge;
      }
    }
  }
}

// ---------------------------------------------------------------------------
extern "C" void kernel_launch(void* const* d_in, const int* in_sizes, int n_in,
                              void* d_out, int out_size, void* d_ws, size_t ws_size,
                              hipStream_t stream) {
  const float* x = (const float*)d_in[0];
  const float* gamma = (const float*)d_in[1];
  const float* beta = (const float*)d_in[2];
  const float* W = (const float*)d_in[3];
  const float* bias = (const float*)d_in[4];
  float* out = (float*)d_out;

  // workspace layout
  float* mu = (float*)d_ws;            // NPIX floats
  float* rs = mu + NPIX;               // NPIX floats
  float* t1 = rs + NPIX;               // 384 floats
  float* t2 = t1 + C_OUT;              // 384 floats
  __bf16* Wp = (__bf16*)(t2 + C_OUT);  // 384*384 bf16

  ppl_stats_kernel<<<NPIX / 512, 256, 0, stream>>>(x, mu, rs);
  ppl_prep_kernel<<<C_OUT, 128, 0, stream>>>(W, gamma, beta, bias, Wp, t1, t2);

  const int grid = (NPIX / BP) * (C_OUT / BO);  // 1024 * 6 = 6144
  ppl_gemm_kernel<<<grid, 256, 0, stream>>>(x, Wp, mu, rs, t1, t2, out);
}

// Round 2
// 166.269 us; speedup vs baseline: 1.6611x; 1.6611x over previous
//
#include <hip/hip_runtime.h>
#include <hip/hip_bf16.h>
#include <cmath>

typedef float f32x4 __attribute__((ext_vector_type(4)));
typedef __bf16 bf16x8 __attribute__((ext_vector_type(8)));

#define C_IN 384
#define C_OUT 384
#define SPB 4096      // spatial per batch image (64*64)
#define NPIX 131072   // 32 * 4096 total pixels
#define BP 64         // pixels per block
#define LDK 392       // padded Xs row length in bf16 (784 B, 16B-aligned, stride 196 words)

// ---------------------------------------------------------------------------
// Kernel 1: fold LN affine into the weights.
//   Wp[o][c] = bf16(W[o][c] * gamma[c])
//   t1[o]    = sum_c float(Wp[o][c])
//   t2[o]    = sum_c beta[c] * W[o][c] + b[o]
// ---------------------------------------------------------------------------
__global__ __launch_bounds__(128) void ppl_prep_kernel(const float* __restrict__ W,
                                                       const float* __restrict__ gamma,
                                                       const float* __restrict__ beta,
                                                       const float* __restrict__ bias,
                                                       __bf16* __restrict__ Wp,
                                                       float* __restrict__ t1,
                                                       float* __restrict__ t2) {
  const int o = blockIdx.x;
  const int t = threadIdx.x;
  const float* row = W + o * C_IN;
  float s1 = 0.f, s2 = 0.f;
  for (int c = t; c < C_IN; c += 128) {
    const float w = row[c];
    const __bf16 wq = (__bf16)(w * gamma[c]);
    Wp[o * C_IN + c] = wq;
    s1 += (float)wq;
    s2 += beta[c] * w;
  }
#pragma unroll
  for (int off = 32; off > 0; off >>= 1) {
    s1 += __shfl_down(s1, off);
    s2 += __shfl_down(s2, off);
  }
  __shared__ float red[2][2];
  if ((t & 63) == 0) { red[t >> 6][0] = s1; red[t >> 6][1] = s2; }
  __syncthreads();
  if (t == 0) {
    t1[o] = red[0][0] + red[1][0];
    t2[o] = red[0][1] + red[1][1] + bias[o];
  }
}

// ---------------------------------------------------------------------------
// Kernel 2: fused stats + GEMM + LN-epilogue + GELU.
//   Block = 64 pixels x ALL 384 out-channels.  x read exactly once.
//   Stage x[64 px][384 ch] as bf16 in LDS, accumulating fp32 sum/sumsq
//   per pixel on the fly (LN stats fused, no pre-pass).
//   GEMM: A = X (M=pixels, from LDS), B = W' (N=out, 16B/lane direct from
//   L2-resident global), MFMA 16x16x32 bf16, fp32 acc.  One barrier total;
//   k-loop is barrier-free.
//   Epilogue: y = rs*(acc - mu*t1[o]) + t2[o]; exact-erf GELU; float4 NCHW
//   stores (C/D reg quad = 4 consecutive pixels).
// ---------------------------------------------------------------------------
__global__ __launch_bounds__(256, 3) void ppl_fused_kernel(const float* __restrict__ x,
                                                           const __bf16* __restrict__ Wp,
                                                           const float* __restrict__ t1g,
                                                           const float* __restrict__ t2g,
                                                           float* __restrict__ out) {
  __shared__ __bf16 Xs[BP][LDK];       // pixel-major, K-contiguous
  __shared__ float ps[4][BP];
  __shared__ float pq[4][BP];
  __shared__ float mu_s[BP];
  __shared__ float rs_s[BP];

  const int tid = threadIdx.x;
  const int w = tid >> 6;      // wave id 0..3
  const int lane = tid & 63;
  const int p0 = blockIdx.x * BP;
  const int b = p0 >> 12;
  const int s0 = p0 & 4095;
  const float* xbase = x + (size_t)b * (C_IN * SPB) + s0;

  // ---- stage full-K x tile + fused LN stats ----
  // wave w owns contiguous channels [w*96, w*96+96); lane = pixel.
  {
    float s = 0.f, q = 0.f;
    const int cb = w * 96;
#pragma unroll
    for (int i = 0; i < 12; ++i) {
      const int c = cb + i * 8;
      bf16x8 pk;
#pragma unroll
      for (int j = 0; j < 8; ++j) {
        const float v = xbase[(size_t)(c + j) * SPB + lane];
        s += v;
        q += v * v;
        pk[j] = (__bf16)v;
      }
      *reinterpret_cast<bf16x8*>(&Xs[lane][c]) = pk;
    }
    ps[w][lane] = s;
    pq[w][lane] = q;
  }
  __syncthreads();
  if (tid < BP) {
    const float st = ps[0][tid] + ps[1][tid] + ps[2][tid] + ps[3][tid];
    const float qt = pq[0][tid] + pq[1][tid] + pq[2][tid] + pq[3][tid];
    const float m = st * (1.0f / C_IN);
    const float var = qt * (1.0f / C_IN) - m * m;
    mu_s[tid] = m;
    rs_s[tid] = rsqrtf(var + 1e-5f);
  }
  __syncthreads();

  // ---- barrier-free k-loop: wave w computes o-rows [w*96, w*96+96) ----
  const int fr = lane & 15;
  const int kg = (lane >> 4) * 8;   // k sub-offset {0,8,16,24}
  const int ob = w * 96;

  f32x4 acc[4][6];
#pragma unroll
  for (int m = 0; m < 4; ++m)
#pragma unroll
    for (int n = 0; n < 6; ++n) acc[m][n] = (f32x4){0.f, 0.f, 0.f, 0.f};

#pragma unroll 2
  for (int k0 = 0; k0 < C_IN; k0 += 32) {
    bf16x8 af[4], bf[6];
#pragma unroll
    for (int m = 0; m < 4; ++m)
      af[m] = *reinterpret_cast<const bf16x8*>(&Xs[m * 16 + fr][k0 + kg]);
#pragma unroll
    for (int n = 0; n < 6; ++n)
      bf[n] = *reinterpret_cast<const bf16x8*>(Wp + (size_t)(ob + n * 16 + fr) * C_IN + k0 + kg);
#pragma unroll
    for (int n = 0; n < 6; ++n)
#pragma unroll
      for (int m = 0; m < 4; ++m)
        acc[m][n] = __builtin_amdgcn_mfma_f32_16x16x32_bf16(af[m], bf[n], acc[m][n], 0, 0, 0);
  }

  // ---- epilogue: LN correction + exact GELU + float4 NCHW stores ----
  const int prow_base = (lane >> 4) * 4;
#pragma unroll
  for (int n = 0; n < 6; ++n) {
    const int o = ob + n * 16 + fr;
    const float t1v = t1g[o];
    const float t2v = t2g[o];
    float* outo = out + (((size_t)(b * C_OUT + o)) << 12) + s0;
#pragma unroll
    for (int m = 0; m < 4; ++m) {
      const int prow = m * 16 + prow_base;
      const f32x4 mu4 = *reinterpret_cast<const f32x4*>(&mu_s[prow]);
      const f32x4 rs4 = *reinterpret_cast<const f32x4*>(&rs_s[prow]);
      f32x4 y;
#pragma unroll
      for (int r = 0; r < 4; ++r) {
        const float val = rs4[r] * (acc[m][n][r] - mu4[r] * t1v) + t2v;
        y[r] = 0.5f * val * (1.0f + erff(val * 0.7071067811865475f));
      }
      *reinterpret_cast<f32x4*>(outo + prow) = y;
    }
  }
}

// ---------------------------------------------------------------------------
extern "C" void kernel_launch(void* const* d_in, const int* in_sizes, int n_in,
                              void* d_out, int out_size, void* d_ws, size_t ws_size,
                              hipStream_t stream) {
  const float* x = (const float*)d_in[0];
  const float* gamma = (const float*)d_in[1];
  const float* beta = (const float*)d_in[2];
  const float* W = (const float*)d_in[3];
  const float* bias = (const float*)d_in[4];
  float* out = (float*)d_out;

  // workspace layout
  __bf16* Wp = (__bf16*)d_ws;                    // 384*384 bf16 = 294912 B
  float* t1 = (float*)(Wp + C_OUT * C_IN);       // 384 floats
  float* t2 = t1 + C_OUT;                        // 384 floats

  ppl_prep_kernel<<<C_OUT, 128, 0, stream>>>(W, gamma, beta, bias, Wp, t1, t2);
  ppl_fused_kernel<<<NPIX / BP, 256, 0, stream>>>(x, Wp, t1, t2, out);
}